// Round 5
// baseline (801.968 us; speedup 1.0000x reference)
//
#include <hip/hip_runtime.h>
#include <hip/hip_bf16.h>
#include <hip/hip_cooperative_groups.h>

namespace cg = cooperative_groups;

#define NN 50000
#define HD 128
#define NL 4
#define BN_EPS 1e-5f
#define NTILES 3125
#define NBLK 196
#define LDS_BYTES 141312

typedef __attribute__((ext_vector_type(8))) short short8;
typedef __attribute__((ext_vector_type(4))) float f32x4;

__device__ inline ushort f2bf(float f){
  uint u = __float_as_uint(f);
  uint r = (u + 0x7fffu + ((u >> 16) & 1u)) >> 16;
  return (ushort)r;
}
__device__ inline float bflo(uint u){ return __uint_as_float(u << 16); }
__device__ inline float bfhi(uint u){ return __uint_as_float(u & 0xffff0000u); }

// ---------------- cast fp32 -> bf16 ----------------
__global__ void cast_f32_bf16x4(const float* __restrict__ in, ushort* __restrict__ out, int n4){
  int i = blockIdx.x * blockDim.x + threadIdx.x;
  int stride = gridDim.x * blockDim.x;
  const float4* in4 = (const float4*)in;
  for (; i < n4; i += stride){
    float4 v = in4[i];
    ushort4 r;
    r.x = f2bf(v.x); r.y = f2bf(v.y); r.z = f2bf(v.z); r.w = f2bf(v.w);
    *(ushort4*)(out + i * 4) = r;
  }
}

__global__ void cast_weights(const float* __restrict__ w1, const float* __restrict__ w2,
                             const float* __restrict__ wf, ushort* __restrict__ wb){
  int i = blockIdx.x * 256 + threadIdx.x;
  if (i >= 36864) return;
  const float* src;
  if (i < 16384)      src = w1 + i * 4;
  else if (i < 32768) src = w2 + (i - 16384) * 4;
  else                src = wf + (i - 32768) * 4;
  float4 v = *(const float4*)src;
  ushort4 r;
  r.x = f2bf(v.x); r.y = f2bf(v.y); r.z = f2bf(v.z); r.w = f2bf(v.w);
  *(ushort4*)(wb + i * 4) = r;
}

// ---------------- CSR build (simple forms — round-2 proven) ----------------
__global__ void hist_kernel(const int* __restrict__ dst, int* __restrict__ deg, int E){
  int e = blockIdx.x * 256 + threadIdx.x;
  if (e < E) atomicAdd(&deg[dst[e]], 1);
}

__global__ void scan1_kernel(const int* __restrict__ deg, int* __restrict__ incl,
                             int* __restrict__ bsum, int n){
  __shared__ int tmp[1024];
  int gid = blockIdx.x * 1024 + threadIdx.x;
  int v = (gid < n) ? deg[gid] : 0;
  tmp[threadIdx.x] = v;
  __syncthreads();
  for (int ofs = 1; ofs < 1024; ofs <<= 1){
    int t = tmp[threadIdx.x];
    int a = (threadIdx.x >= ofs) ? tmp[threadIdx.x - ofs] : 0;
    __syncthreads();
    tmp[threadIdx.x] = t + a;
    __syncthreads();
  }
  if (gid < n) incl[gid] = tmp[threadIdx.x];
  if (threadIdx.x == 1023) bsum[blockIdx.x] = tmp[1023];
}

__global__ void scan2_kernel(const int* __restrict__ bsum, int* __restrict__ base,
                             int* __restrict__ off, int nb, int n){
  if (threadIdx.x == 0){
    int run = 0;
    for (int i = 0; i < nb; ++i){ base[i] = run; run += bsum[i]; }
    off[n] = run;
  }
}

__global__ void scan3_kernel(const int* __restrict__ deg, const int* __restrict__ incl,
                             const int* __restrict__ base, int* __restrict__ off, int n){
  int gid = blockIdx.x * 1024 + threadIdx.x;
  if (gid < n) off[gid] = incl[gid] - deg[gid] + base[blockIdx.x];
}

__global__ void fill_kernel(const int* __restrict__ src, const int* __restrict__ dst,
                            const int* __restrict__ off, int* __restrict__ cur,
                            int* __restrict__ csrc, int E){
  int e = blockIdx.x * 256 + threadIdx.x;
  if (e < E){
    int d = dst[e];
    int p = atomicAdd(&cur[d], 1);
    csrc[off[d] + p] = src[e];
  }
}

// ---------------- the whole GIN stack: one cooperative kernel ----------------
// 196 blocks x 1024 threads (16 waves, 1 MFMA 16-row tile per wave).
// LDS (dynamic 141312 B): W1 34816 | W2 34816 | per-wave scratch 16x4352 | sS/sT/ssum/ssq 2048
// 1 block/CU by LDS; grid 196 <= 256 CUs -> cooperative co-residency holds.
__global__ __launch_bounds__(1024) void layers_kernel(
    ushort* __restrict__ xb, const int* __restrict__ off, const int* __restrict__ csrc,
    const ushort* __restrict__ wb, float* __restrict__ stats,
    const float* __restrict__ fc1_b, const float* __restrict__ bn1_g, const float* __restrict__ bn1_b,
    const float* __restrict__ fc2_b, const float* __restrict__ bn2_g,
    const float* __restrict__ bn3_g, const float* __restrict__ bn3_b,
    const float* __restrict__ fc_b, float* __restrict__ out)
{
  extern __shared__ char dyn[];
  uint4* w1 = (uint4*)dyn;                     // 2176 uint4
  uint4* w2 = (uint4*)(dyn + 34816);           // 2176 uint4
  uint*  scrAll = (uint*)(dyn + 69632);        // 16 waves x 1088 uint (16 rows x 68)
  float* sS  = (float*)(dyn + 139264);
  float* sT  = sS + 128;
  float* ssum = sT + 128;
  float* ssq  = ssum + 128;

  cg::grid_group grid = cg::this_grid();
  const int tid = threadIdx.x;
  const int wave = tid >> 6, lane = tid & 63;
  const int m = lane & 15, q = lane >> 4;
  const int tile = blockIdx.x * 16 + wave;
  const bool tv = tile < NTILES;
  uint* myscr = scrAll + wave * 1088;
  const uint* xr = (const uint*)xb;
  uint* xw = (uint*)xb;
  const float invN = 1.f / (float)NN;

  for (int L = 0; L < NL; ++L){
    // stage this layer's weights
    const uint4* W1g = (const uint4*)wb + L * 2048;
    const uint4* W2g = (const uint4*)wb + 8192 + L * 2048;
    for (int c = tid; c < 2048; c += 1024){
      int d = (c >> 4) * 17 + (c & 15);
      w1[d] = W1g[c];
      w2[d] = W2g[c];
    }
    if (tid < 128){ ssum[tid] = 0.f; ssq[tid] = 0.f; }
    __syncthreads();

    // ---- phase 0: gather h = x + sum(neigh) into per-wave scratch, build A-frags
    short8 af[4];
    if (tv){
      for (int r = 0; r < 16; ++r){
        int node = tile * 16 + r;
        uint self = xr[node * 64 + lane];
        float ax = bflo(self), ay = bfhi(self);
        int s = off[node], e = off[node + 1];
        int j = s;
        for (; j + 8 <= e; j += 8){
          uint v0 = xr[csrc[j+0]*64+lane], v1 = xr[csrc[j+1]*64+lane];
          uint v2 = xr[csrc[j+2]*64+lane], v3 = xr[csrc[j+3]*64+lane];
          uint v4 = xr[csrc[j+4]*64+lane], v5 = xr[csrc[j+5]*64+lane];
          uint v6 = xr[csrc[j+6]*64+lane], v7 = xr[csrc[j+7]*64+lane];
          ax += bflo(v0)+bflo(v1)+bflo(v2)+bflo(v3)+bflo(v4)+bflo(v5)+bflo(v6)+bflo(v7);
          ay += bfhi(v0)+bfhi(v1)+bfhi(v2)+bfhi(v3)+bfhi(v4)+bfhi(v5)+bfhi(v6)+bfhi(v7);
        }
        for (; j + 4 <= e; j += 4){
          uint v0 = xr[csrc[j+0]*64+lane], v1 = xr[csrc[j+1]*64+lane];
          uint v2 = xr[csrc[j+2]*64+lane], v3 = xr[csrc[j+3]*64+lane];
          ax += bflo(v0)+bflo(v1)+bflo(v2)+bflo(v3);
          ay += bfhi(v0)+bfhi(v1)+bfhi(v2)+bfhi(v3);
        }
        for (; j < e; ++j){ uint v = xr[csrc[j]*64+lane]; ax += bflo(v); ay += bfhi(v); }
        myscr[r * 68 + lane] = (uint)f2bf(ax) | ((uint)f2bf(ay) << 16);
      }
#pragma unroll
      for (int kt = 0; kt < 4; ++kt){
        uint4 t = *(const uint4*)(myscr + m * 68 + kt * 16 + q * 4);
        af[kt] = *(short8*)&t;
      }
    }

    // ---- phase 1: fc1 MFMA + bias + stats1
    f32x4 acc[8];
#pragma unroll
    for (int i = 0; i < 8; ++i) acc[i] = (f32x4)0.f;
    if (tv){
#pragma unroll
      for (int kt = 0; kt < 4; ++kt){
#pragma unroll
        for (int to = 0; to < 8; ++to){
          uint4 bw = w1[(to*16+m)*17 + kt*4 + q];
          acc[to] = __builtin_amdgcn_mfma_f32_16x16x32_bf16(af[kt], *(short8*)&bw, acc[to], 0,0,0);
        }
      }
      const float* b1 = fc1_b + L*128;
#pragma unroll
      for (int to = 0; to < 8; ++to){
        float bc = b1[to*16+m];
#pragma unroll
        for (int r = 0; r < 4; ++r) acc[to][r] += bc;
      }
    }
#pragma unroll
    for (int to = 0; to < 8; ++to){
      float ls = 0.f, lq = 0.f;
      if (tv){
#pragma unroll
        for (int r = 0; r < 4; ++r){ float v = acc[to][r]; ls += v; lq += v*v; }
      }
      ls += __shfl_xor(ls, 16); lq += __shfl_xor(lq, 16);
      ls += __shfl_xor(ls, 32); lq += __shfl_xor(lq, 32);
      if (tv && q == 0){ atomicAdd(&ssum[to*16+m], ls); atomicAdd(&ssq[to*16+m], lq); }
    }
    __syncthreads();
    float* gst = stats + L * 512;
    if (tid < 128){
      atomicAdd(&gst[tid], ssum[tid]);
      atomicAdd(&gst[128 + tid], ssq[tid]);
    }
    grid.sync();

    // ---- phase 2: bn1 affine+relu in-register, repack to A-layout via scratch
    if (tid < 128){
      float mu = gst[tid] * invN;
      float var = fmaxf(gst[128+tid]*invN - mu*mu, 0.f);
      float S = bn1_g[L*128+tid] * rsqrtf(var + BN_EPS);
      sS[tid] = S; sT[tid] = bn1_b[L*128+tid] - mu * S;
      ssum[tid] = 0.f; ssq[tid] = 0.f;
    }
    __syncthreads();
    if (tv){
#pragma unroll
      for (int to = 0; to < 8; ++to){
        int col = to*16 + m;
        float S = sS[col], T = sT[col];
#pragma unroll
        for (int r = 0; r < 4; ++r){
          float v = fmaxf(acc[to][r]*S + T, 0.f);
          uint u = f2bf(v);
          uint other = (uint)__shfl_xor((int)u, 1);
          if (!(m & 1)) myscr[(q*4+r)*68 + to*8 + (m>>1)] = u | (other << 16);
        }
      }
#pragma unroll
      for (int kt = 0; kt < 4; ++kt){
        uint4 t = *(const uint4*)(myscr + m * 68 + kt * 16 + q * 4);
        af[kt] = *(short8*)&t;
      }
    }

    // ---- phase 3: fc2 MFMA + bias + stats2
#pragma unroll
    for (int i = 0; i < 8; ++i) acc[i] = (f32x4)0.f;
    if (tv){
#pragma unroll
      for (int kt = 0; kt < 4; ++kt){
#pragma unroll
        for (int to = 0; to < 8; ++to){
          uint4 bw = w2[(to*16+m)*17 + kt*4 + q];
          acc[to] = __builtin_amdgcn_mfma_f32_16x16x32_bf16(af[kt], *(short8*)&bw, acc[to], 0,0,0);
        }
      }
      const float* b2 = fc2_b + L*128;
#pragma unroll
      for (int to = 0; to < 8; ++to){
        float bc = b2[to*16+m];
#pragma unroll
        for (int r = 0; r < 4; ++r) acc[to][r] += bc;
      }
    }
#pragma unroll
    for (int to = 0; to < 8; ++to){
      float ls = 0.f, lq = 0.f;
      if (tv){
#pragma unroll
        for (int r = 0; r < 4; ++r){ float v = acc[to][r]; ls += v; lq += v*v; }
      }
      ls += __shfl_xor(ls, 16); lq += __shfl_xor(lq, 16);
      ls += __shfl_xor(ls, 32); lq += __shfl_xor(lq, 32);
      if (tv && q == 0){ atomicAdd(&ssum[to*16+m], ls); atomicAdd(&ssq[to*16+m], lq); }
    }
    __syncthreads();
    float* gst2 = stats + L * 512 + 256;
    if (tid < 128){
      atomicAdd(&gst2[tid], ssum[tid]);
      atomicAdd(&gst2[128 + tid], ssq[tid]);
    }
    grid.sync();

    // ---- phase 4: composed bn3(bn2(.))+relu -> write xb (bf16)
    if (tid < 128){
      float mu = gst2[tid]*invN;
      float var = fmaxf(gst2[128+tid]*invN - mu*mu, 0.f);
      float inv2 = rsqrtf(var + BN_EPS);
      float ttv = bn2_g[L*128+tid]*inv2;
      float inv3 = rsqrtf(ttv*ttv*var + BN_EPS);
      float S = ttv*inv3*bn3_g[L*128+tid];
      sS[tid] = S; sT[tid] = bn3_b[L*128+tid] - mu*S;
    }
    __syncthreads();
    if (tv){
#pragma unroll
      for (int to = 0; to < 8; ++to){
        int col = to*16 + m;
        float S = sS[col], T = sT[col];
#pragma unroll
        for (int r = 0; r < 4; ++r){
          float v = fmaxf(acc[to][r]*S + T, 0.f);
          uint u = f2bf(v);
          uint other = (uint)__shfl_xor((int)u, 1);
          if (!(m & 1)) myscr[(q*4+r)*68 + to*8 + (m>>1)] = u | (other << 16);
        }
      }
      for (int r2 = 0; r2 < 16; ++r2){
        xw[(tile*16 + r2)*64 + lane] = myscr[r2*68 + lane];
      }
    }
    grid.sync();
  }

  // ---- classifier: out = xb @ fc_w^T + fc_b (f32 out)
  {
    const uint4* Wfg = (const uint4*)wb + 16384;
    for (int c = tid; c < 2048; c += 1024){
      w1[(c >> 4) * 17 + (c & 15)] = Wfg[c];
    }
    __syncthreads();
    if (tv){
      short8 af[4];
      const uint4* A4 = (const uint4*)xb;
#pragma unroll
      for (int kt = 0; kt < 4; ++kt){
        uint4 t = A4[(tile*16+m)*16 + kt*4 + q];
        af[kt] = *(short8*)&t;
      }
      f32x4 acc[8];
#pragma unroll
      for (int i = 0; i < 8; ++i) acc[i] = (f32x4)0.f;
#pragma unroll
      for (int kt = 0; kt < 4; ++kt){
#pragma unroll
        for (int to = 0; to < 8; ++to){
          uint4 bw = w1[(to*16+m)*17 + kt*4 + q];
          acc[to] = __builtin_amdgcn_mfma_f32_16x16x32_bf16(af[kt], *(short8*)&bw, acc[to], 0,0,0);
        }
      }
#pragma unroll
      for (int to = 0; to < 8; ++to){
        int col = to*16+m;
        float bc = fc_b[col];
#pragma unroll
        for (int r = 0; r < 4; ++r)
          out[(tile*16 + q*4 + r)*128 + col] = acc[to][r] + bc;
      }
    }
  }
}

extern "C" void kernel_launch(void* const* d_in, const int* in_sizes, int n_in,
                              void* d_out, int out_size, void* d_ws, size_t ws_size,
                              hipStream_t stream) {
  const float* x     = (const float*)d_in[0];
  const int*   ei    = (const int*)d_in[1];
  const float* fc1_w = (const float*)d_in[2];
  const float* fc1_b = (const float*)d_in[3];
  const float* bn1_g = (const float*)d_in[4];
  const float* bn1_b = (const float*)d_in[5];
  const float* fc2_w = (const float*)d_in[6];
  const float* fc2_b = (const float*)d_in[7];
  const float* bn2_g = (const float*)d_in[8];
  const float* bn3_g = (const float*)d_in[10];
  const float* bn3_b = (const float*)d_in[11];
  const float* fc_w  = (const float*)d_in[12];
  const float* fc_b  = (const float*)d_in[13];

  int E = in_sizes[1] / 2;
  const int* srcp = ei;
  const int* dstp = ei + E;

  char* ws = (char*)d_ws;
  int*    off    = (int*)(ws + 0);            // (N+1) ints
  int*    deg    = (int*)(ws + 200064);       // N ints
  int*    cur    = (int*)(ws + 400128);       // N ints
  int*    csrc   = (int*)(ws + 600192);       // E ints (aliased as `incl` pre-fill)
  ushort* wb     = (ushort*)(ws + 3800192);   // 147456 bf16
  float*  stats  = (float*)(ws + 4095104);    // 8 slices x 256
  float*  params = (float*)(ws + 4103296);    // scan scratch (bsum/base)
  ushort* xb     = (ushort*)(ws + 4111488);   // N*128 bf16

  int* incl = csrc;
  int* bsum = (int*)params;
  int* base = (int*)params + 64;

  hipMemsetAsync(deg, 0, 400128, stream);     // deg + cur
  hipMemsetAsync(stats, 0, 8192, stream);

  cast_f32_bf16x4<<<2048, 256, 0, stream>>>(x, xb, NN * HD / 4);
  cast_weights<<<144, 256, 0, stream>>>(fc1_w, fc2_w, fc_w, wb);

  int eb = (E + 255) / 256;
  const int SB = (NN + 1023) / 1024;
  hist_kernel<<<eb, 256, 0, stream>>>(dstp, deg, E);
  scan1_kernel<<<SB, 1024, 0, stream>>>(deg, incl, bsum, NN);
  scan2_kernel<<<1, 64, 0, stream>>>(bsum, base, off, SB, NN);
  scan3_kernel<<<SB, 1024, 0, stream>>>(deg, incl, base, off, NN);
  fill_kernel<<<eb, 256, 0, stream>>>(srcp, dstp, off, cur, csrc, E);

  hipFuncSetAttribute((const void*)layers_kernel,
                      hipFuncAttributeMaxDynamicSharedMemorySize, LDS_BYTES);

  ushort* xbp = xb;
  const int* offp = off;
  const int* csrcp = csrc;
  const ushort* wbp = wb;
  float* statsp = stats;
  float* outp = (float*)d_out;
  void* args[] = { &xbp, &offp, &csrcp, &wbp, &statsp,
                   (void*)&fc1_b, (void*)&bn1_g, (void*)&bn1_b,
                   (void*)&fc2_b, (void*)&bn2_g,
                   (void*)&bn3_g, (void*)&bn3_b,
                   (void*)&fc_b, &outp };
  hipLaunchCooperativeKernel((const void*)layers_kernel, dim3(NBLK), dim3(1024),
                             args, LDS_BYTES, stream);
}

// Round 6
// 650.413 us; speedup vs baseline: 1.2330x; 1.2330x over previous
//
#include <hip/hip_runtime.h>
#include <hip/hip_bf16.h>
#include <hip/hip_cooperative_groups.h>

namespace cg = cooperative_groups;

#define NN 50000
#define HD 128
#define NL 4
#define BN_EPS 1e-5f
#define NTILES 3125
#define NBLK 196
#define LDS_BYTES 141312

typedef __attribute__((ext_vector_type(8))) short short8;
typedef __attribute__((ext_vector_type(4))) float f32x4;

__device__ inline ushort f2bf(float f){
  uint u = __float_as_uint(f);
  uint r = (u + 0x7fffu + ((u >> 16) & 1u)) >> 16;
  return (ushort)r;
}
__device__ inline float bflo(uint u){ return __uint_as_float(u << 16); }
__device__ inline float bfhi(uint u){ return __uint_as_float(u & 0xffff0000u); }

// ---------------- cast fp32 -> bf16 ----------------
__global__ void cast_f32_bf16x4(const float* __restrict__ in, ushort* __restrict__ out, int n4){
  int i = blockIdx.x * blockDim.x + threadIdx.x;
  int stride = gridDim.x * blockDim.x;
  const float4* in4 = (const float4*)in;
  for (; i < n4; i += stride){
    float4 v = in4[i];
    ushort4 r;
    r.x = f2bf(v.x); r.y = f2bf(v.y); r.z = f2bf(v.z); r.w = f2bf(v.w);
    *(ushort4*)(out + i * 4) = r;
  }
}

__global__ void cast_weights(const float* __restrict__ w1, const float* __restrict__ w2,
                             const float* __restrict__ wf, ushort* __restrict__ wb){
  int i = blockIdx.x * 256 + threadIdx.x;
  if (i >= 36864) return;
  const float* src;
  if (i < 16384)      src = w1 + i * 4;
  else if (i < 32768) src = w2 + (i - 16384) * 4;
  else                src = wf + (i - 32768) * 4;
  float4 v = *(const float4*)src;
  ushort4 r;
  r.x = f2bf(v.x); r.y = f2bf(v.y); r.z = f2bf(v.z); r.w = f2bf(v.w);
  *(ushort4*)(wb + i * 4) = r;
}

// ---------------- CSR build: fill1 (hist+slot), scan, fill2 (no atomics) ----------------
__global__ void fill1_kernel(const int* __restrict__ dst, int* __restrict__ cnt,
                             int* __restrict__ pos, int E){
  int e = blockIdx.x * 256 + threadIdx.x;
  if (e < E){
    pos[e] = atomicAdd(&cnt[dst[e]], 1);
  }
}

__global__ void scan1_kernel(const int* __restrict__ deg, int* __restrict__ incl,
                             int* __restrict__ bsum, int n){
  __shared__ int tmp[1024];
  int gid = blockIdx.x * 1024 + threadIdx.x;
  int v = (gid < n) ? deg[gid] : 0;
  tmp[threadIdx.x] = v;
  __syncthreads();
  for (int ofs = 1; ofs < 1024; ofs <<= 1){
    int t = tmp[threadIdx.x];
    int a = (threadIdx.x >= ofs) ? tmp[threadIdx.x - ofs] : 0;
    __syncthreads();
    tmp[threadIdx.x] = t + a;
    __syncthreads();
  }
  if (gid < n) incl[gid] = tmp[threadIdx.x];
  if (threadIdx.x == 1023) bsum[blockIdx.x] = tmp[1023];
}

__global__ void scan2_kernel(const int* __restrict__ bsum, int* __restrict__ base,
                             int* __restrict__ off, int nb, int n){
  if (threadIdx.x == 0){
    int run = 0;
    for (int i = 0; i < nb; ++i){ base[i] = run; run += bsum[i]; }
    off[n] = run;
  }
}

__global__ void scan3_kernel(const int* __restrict__ deg, const int* __restrict__ incl,
                             const int* __restrict__ base, int* __restrict__ off, int n){
  int gid = blockIdx.x * 1024 + threadIdx.x;
  if (gid < n) off[gid] = incl[gid] - deg[gid] + base[blockIdx.x];
}

__global__ void fill2_kernel(const int* __restrict__ src, const int* __restrict__ dst,
                             const int* __restrict__ off, const int* __restrict__ pos,
                             int* __restrict__ csrc, int E){
  int e = blockIdx.x * 256 + threadIdx.x;
  if (e < E){
    csrc[off[dst[e]] + pos[e]] = src[e];
  }
}

// ---------------- aggregation: one wave per node (TLP hides gather latency) ----------------
__global__ __launch_bounds__(256) void agg_kernel(const ushort* __restrict__ xb,
                                                  const int* __restrict__ off,
                                                  const int* __restrict__ csrc,
                                                  ushort* __restrict__ h){
  int node = blockIdx.x * 4 + (threadIdx.x >> 6);
  int lane = threadIdx.x & 63;
  const uint* xr = (const uint*)xb;
  uint self = xr[node * 64 + lane];
  float ax = bflo(self), ay = bfhi(self);
  int s = off[node], e = off[node + 1];
  int j = s;
  for (; j + 8 <= e; j += 8){
    uint v0 = xr[csrc[j+0]*64+lane], v1 = xr[csrc[j+1]*64+lane];
    uint v2 = xr[csrc[j+2]*64+lane], v3 = xr[csrc[j+3]*64+lane];
    uint v4 = xr[csrc[j+4]*64+lane], v5 = xr[csrc[j+5]*64+lane];
    uint v6 = xr[csrc[j+6]*64+lane], v7 = xr[csrc[j+7]*64+lane];
    ax += bflo(v0)+bflo(v1)+bflo(v2)+bflo(v3)+bflo(v4)+bflo(v5)+bflo(v6)+bflo(v7);
    ay += bfhi(v0)+bfhi(v1)+bfhi(v2)+bfhi(v3)+bfhi(v4)+bfhi(v5)+bfhi(v6)+bfhi(v7);
  }
  for (; j + 4 <= e; j += 4){
    uint v0 = xr[csrc[j+0]*64+lane], v1 = xr[csrc[j+1]*64+lane];
    uint v2 = xr[csrc[j+2]*64+lane], v3 = xr[csrc[j+3]*64+lane];
    ax += bflo(v0)+bflo(v1)+bflo(v2)+bflo(v3);
    ay += bfhi(v0)+bfhi(v1)+bfhi(v2)+bfhi(v3);
  }
  for (; j < e; ++j){
    uint v = xr[csrc[j] * 64 + lane];
    ax += bflo(v); ay += bfhi(v);
  }
  uint o = (uint)f2bf(ax) | ((uint)f2bf(ay) << 16);
  ((uint*)h)[node * 64 + lane] = o;
}

// ---------------- one GIN layer (cooperative): fc1 -> bn1 -> fc2 -> bn23 -> xb ----------------
// 196 blocks x 1024 threads (16 waves, 1 MFMA row-tile each). Accumulators stay in
// registers across both GEMMs and all three BNs; only input hb and output xb touch global.
// Last layer: keep A-frags and run the classifier in-kernel (no xb write).
__global__ __launch_bounds__(1024) void layer_kernel(
    const ushort* __restrict__ hb, ushort* __restrict__ xb,
    const ushort* __restrict__ w1g, const ushort* __restrict__ w2g,
    const ushort* __restrict__ wfg, float* __restrict__ gstAll,
    const float* __restrict__ b1v, const float* __restrict__ g1v, const float* __restrict__ bb1v,
    const float* __restrict__ b2v, const float* __restrict__ g2v,
    const float* __restrict__ g3v, const float* __restrict__ b3v,
    const float* __restrict__ fcb, float* __restrict__ out, int last)
{
  extern __shared__ char dyn[];
  uint4* w1 = (uint4*)dyn;                     // 2176 uint4 (17-stride pad)
  uint4* w2 = (uint4*)(dyn + 34816);
  uint*  scrAll = (uint*)(dyn + 69632);        // 16 waves x 1088 uint (16 rows x 68)
  float* sS  = (float*)(dyn + 139264);
  float* sT  = sS + 128;
  float* ssum = sT + 128;
  float* ssq  = ssum + 128;

  cg::grid_group grid = cg::this_grid();
  const int tid = threadIdx.x;
  const int wave = tid >> 6, lane = tid & 63;
  const int m = lane & 15, q = lane >> 4;
  const int tile = blockIdx.x * 16 + wave;
  const bool tv = tile < NTILES;
  uint* myscr = scrAll + wave * 1088;
  const float invN = 1.f / (float)NN;

  // stage weights
  {
    const uint4* W1g = (const uint4*)w1g;
    const uint4* W2g = (const uint4*)w2g;
    for (int c = tid; c < 2048; c += 1024){
      int d = (c >> 4) * 17 + (c & 15);
      w1[d] = W1g[c];
      w2[d] = W2g[c];
    }
  }
  if (tid < 128){ ssum[tid] = 0.f; ssq[tid] = 0.f; }
  __syncthreads();

  // A-frags from hb
  short8 af[4];
  if (tv){
    const uint4* A4 = (const uint4*)hb;
#pragma unroll
    for (int kt = 0; kt < 4; ++kt){
      uint4 t = A4[(tile*16 + m)*16 + kt*4 + q];
      af[kt] = *(short8*)&t;
    }
  }

  // ---- fc1 MFMA + bias + stats1
  f32x4 acc[8];
#pragma unroll
  for (int i = 0; i < 8; ++i) acc[i] = (f32x4)0.f;
  if (tv){
#pragma unroll
    for (int kt = 0; kt < 4; ++kt){
#pragma unroll
      for (int to = 0; to < 8; ++to){
        uint4 bw = w1[(to*16+m)*17 + kt*4 + q];
        acc[to] = __builtin_amdgcn_mfma_f32_16x16x32_bf16(af[kt], *(short8*)&bw, acc[to], 0,0,0);
      }
    }
#pragma unroll
    for (int to = 0; to < 8; ++to){
      float bc = b1v[to*16+m];
#pragma unroll
      for (int r = 0; r < 4; ++r) acc[to][r] += bc;
    }
  }
#pragma unroll
  for (int to = 0; to < 8; ++to){
    float ls = 0.f, lq = 0.f;
    if (tv){
#pragma unroll
      for (int r = 0; r < 4; ++r){ float v = acc[to][r]; ls += v; lq += v*v; }
    }
    ls += __shfl_xor(ls, 16); lq += __shfl_xor(lq, 16);
    ls += __shfl_xor(ls, 32); lq += __shfl_xor(lq, 32);
    if (tv && q == 0){ atomicAdd(&ssum[to*16+m], ls); atomicAdd(&ssq[to*16+m], lq); }
  }
  __syncthreads();
  float* gst = gstAll;
  if (tid < 128){
    atomicAdd(&gst[tid], ssum[tid]);
    atomicAdd(&gst[128 + tid], ssq[tid]);
  }
  grid.sync();

  // ---- bn1 affine+relu in-register, repack to A-layout
  if (tid < 128){
    float mu = gst[tid] * invN;
    float var = fmaxf(gst[128+tid]*invN - mu*mu, 0.f);
    float S = g1v[tid] * rsqrtf(var + BN_EPS);
    sS[tid] = S; sT[tid] = bb1v[tid] - mu * S;
    ssum[tid] = 0.f; ssq[tid] = 0.f;
  }
  __syncthreads();
  if (tv){
#pragma unroll
    for (int to = 0; to < 8; ++to){
      int col = to*16 + m;
      float S = sS[col], T = sT[col];
#pragma unroll
      for (int r = 0; r < 4; ++r){
        float v = fmaxf(acc[to][r]*S + T, 0.f);
        uint u = f2bf(v);
        uint other = (uint)__shfl_xor((int)u, 1);
        if (!(m & 1)) myscr[(q*4+r)*68 + to*8 + (m>>1)] = u | (other << 16);
      }
    }
#pragma unroll
    for (int kt = 0; kt < 4; ++kt){
      uint4 t = *(const uint4*)(myscr + m * 68 + kt * 16 + q * 4);
      af[kt] = *(short8*)&t;
    }
  }

  // ---- fc2 MFMA + bias + stats2
#pragma unroll
  for (int i = 0; i < 8; ++i) acc[i] = (f32x4)0.f;
  if (tv){
#pragma unroll
    for (int kt = 0; kt < 4; ++kt){
#pragma unroll
      for (int to = 0; to < 8; ++to){
        uint4 bw = w2[(to*16+m)*17 + kt*4 + q];
        acc[to] = __builtin_amdgcn_mfma_f32_16x16x32_bf16(af[kt], *(short8*)&bw, acc[to], 0,0,0);
      }
    }
#pragma unroll
    for (int to = 0; to < 8; ++to){
      float bc = b2v[to*16+m];
#pragma unroll
      for (int r = 0; r < 4; ++r) acc[to][r] += bc;
    }
  }
#pragma unroll
  for (int to = 0; to < 8; ++to){
    float ls = 0.f, lq = 0.f;
    if (tv){
#pragma unroll
      for (int r = 0; r < 4; ++r){ float v = acc[to][r]; ls += v; lq += v*v; }
    }
    ls += __shfl_xor(ls, 16); lq += __shfl_xor(lq, 16);
    ls += __shfl_xor(ls, 32); lq += __shfl_xor(lq, 32);
    if (tv && q == 0){ atomicAdd(&ssum[to*16+m], ls); atomicAdd(&ssq[to*16+m], lq); }
  }
  __syncthreads();
  float* gst2 = gstAll + 256;
  if (tid < 128){
    atomicAdd(&gst2[tid], ssum[tid]);
    atomicAdd(&gst2[128 + tid], ssq[tid]);
  }
  grid.sync();

  // ---- composed bn3(bn2(.)) + relu
  if (tid < 128){
    float mu = gst2[tid]*invN;
    float var = fmaxf(gst2[128+tid]*invN - mu*mu, 0.f);
    float inv2 = rsqrtf(var + BN_EPS);
    float ttv = g2v[tid]*inv2;
    float inv3 = rsqrtf(ttv*ttv*var + BN_EPS);
    float S = ttv*inv3*g3v[tid];
    sS[tid] = S; sT[tid] = b3v[tid] - mu*S;
  }
  __syncthreads();
  if (tv){
#pragma unroll
    for (int to = 0; to < 8; ++to){
      int col = to*16 + m;
      float S = sS[col], T = sT[col];
#pragma unroll
      for (int r = 0; r < 4; ++r){
        float v = fmaxf(acc[to][r]*S + T, 0.f);
        uint u = f2bf(v);
        uint other = (uint)__shfl_xor((int)u, 1);
        if (!(m & 1)) myscr[(q*4+r)*68 + to*8 + (m>>1)] = u | (other << 16);
      }
    }
  }

  if (!last){
    if (tv){
      uint* xw = (uint*)xb;
      for (int r2 = 0; r2 < 16; ++r2){
        xw[(tile*16 + r2)*64 + lane] = myscr[r2*68 + lane];
      }
    }
    return;
  }

  // ---- classifier (last layer): A-frags from scratch, wf staged over w1
  if (tv){
#pragma unroll
    for (int kt = 0; kt < 4; ++kt){
      uint4 t = *(const uint4*)(myscr + m * 68 + kt * 16 + q * 4);
      af[kt] = *(short8*)&t;
    }
  }
  __syncthreads();   // everyone done with w1 long ago; barrier before restage
  {
    const uint4* Wfg = (const uint4*)wfg;
    for (int c = tid; c < 2048; c += 1024){
      w1[(c >> 4) * 17 + (c & 15)] = Wfg[c];
    }
  }
  __syncthreads();
  if (tv){
#pragma unroll
    for (int i = 0; i < 8; ++i) acc[i] = (f32x4)0.f;
#pragma unroll
    for (int kt = 0; kt < 4; ++kt){
#pragma unroll
      for (int to = 0; to < 8; ++to){
        uint4 bw = w1[(to*16+m)*17 + kt*4 + q];
        acc[to] = __builtin_amdgcn_mfma_f32_16x16x32_bf16(af[kt], *(short8*)&bw, acc[to], 0,0,0);
      }
    }
#pragma unroll
    for (int to = 0; to < 8; ++to){
      int col = to*16+m;
      float bc = fcb[col];
#pragma unroll
      for (int r = 0; r < 4; ++r)
        out[(tile*16 + q*4 + r)*128 + col] = acc[to][r] + bc;
    }
  }
}

extern "C" void kernel_launch(void* const* d_in, const int* in_sizes, int n_in,
                              void* d_out, int out_size, void* d_ws, size_t ws_size,
                              hipStream_t stream) {
  const float* x     = (const float*)d_in[0];
  const int*   ei    = (const int*)d_in[1];
  const float* fc1_w = (const float*)d_in[2];
  const float* fc1_b = (const float*)d_in[3];
  const float* bn1_g = (const float*)d_in[4];
  const float* bn1_b = (const float*)d_in[5];
  const float* fc2_w = (const float*)d_in[6];
  const float* fc2_b = (const float*)d_in[7];
  const float* bn2_g = (const float*)d_in[8];
  const float* bn3_g = (const float*)d_in[10];
  const float* bn3_b = (const float*)d_in[11];
  const float* fc_w  = (const float*)d_in[12];
  const float* fc_b  = (const float*)d_in[13];

  int E = in_sizes[1] / 2;
  const int* srcp = ei;
  const int* dstp = ei + E;

  char* ws = (char*)d_ws;
  int*    off   = (int*)(ws + 0);           // N+1 ints
  int*    cnt   = (int*)(ws + 200064);      // N ints
  int*    pos   = (int*)(ws + 400128);      // E ints
  int*    csrc  = (int*)(ws + 3600128);     // E ints (aliased as scan `incl` pre-fill2)
  ushort* wb    = (ushort*)(ws + 6800128);  // 147456 bf16
  float*  stats = (float*)(ws + 7095040);   // 4 layers x 512 floats
  int*    sscr  = (int*)(ws + 7103232);     // scan bsum/base (1 KB)
  ushort* xb    = (ushort*)(ws + 7104256);  // N*128 bf16
  ushort* hb    = (ushort*)(ws + 19904256); // N*128 bf16

  int* incl = csrc;
  int* bsum = sscr;
  int* base = sscr + 64;

  hipMemsetAsync(cnt, 0, 200064, stream);
  hipMemsetAsync(stats, 0, 8192, stream);

  cast_f32_bf16x4<<<2048, 256, 0, stream>>>(x, xb, NN * HD / 4);
  cast_weights<<<144, 256, 0, stream>>>(fc1_w, fc2_w, fc_w, wb);

  int eb = (E + 255) / 256;
  const int SB = (NN + 1023) / 1024;
  fill1_kernel<<<eb, 256, 0, stream>>>(dstp, cnt, pos, E);
  scan1_kernel<<<SB, 1024, 0, stream>>>(cnt, incl, bsum, NN);
  scan2_kernel<<<1, 64, 0, stream>>>(bsum, base, off, SB, NN);
  scan3_kernel<<<SB, 1024, 0, stream>>>(cnt, incl, base, off, NN);
  fill2_kernel<<<eb, 256, 0, stream>>>(srcp, dstp, off, pos, csrc, E);

  hipFuncSetAttribute((const void*)layer_kernel,
                      hipFuncAttributeMaxDynamicSharedMemorySize, LDS_BYTES);

  for (int L = 0; L < NL; ++L){
    agg_kernel<<<NN / 4, 256, 0, stream>>>(xb, off, csrc, hb);

    const ushort* hbp = hb;
    ushort* xbp = xb;
    const ushort* w1g = wb + L * 16384;
    const ushort* w2g = wb + 65536 + L * 16384;
    const ushort* wfg = wb + 131072;
    float* gst = stats + L * 512;
    const float* b1v = fc1_b + L * 128;
    const float* g1v = bn1_g + L * 128;
    const float* bb1v = bn1_b + L * 128;
    const float* b2v = fc2_b + L * 128;
    const float* g2v = bn2_g + L * 128;
    const float* g3v = bn3_g + L * 128;
    const float* b3v = bn3_b + L * 128;
    const float* fcbp = fc_b;
    float* outp = (float*)d_out;
    int last = (L == NL - 1) ? 1 : 0;
    void* args[] = { &hbp, &xbp, &w1g, &w2g, &wfg, &gst,
                     &b1v, &g1v, &bb1v, &b2v, &g2v, &g3v, &b3v,
                     &fcbp, &outp, &last };
    hipLaunchCooperativeKernel((const void*)layer_kernel, dim3(NBLK), dim3(1024),
                               args, LDS_BYTES, stream);
  }
}